// Round 1
// baseline (498.183 us; speedup 1.0000x reference)
//
#include <hip/hip_runtime.h>

#define BATCH 2
#define CDIM 256
#define NPIX 2304      // 48*48
#define NHEAD 8
#define DH 64
#define HID 512
#define NMEM 4
#define NKV 2308       // NMEM + NPIX
#define QSCALE 0.125f  // 64^-0.5

typedef float f32x4 __attribute__((ext_vector_type(4)));
typedef __bf16 bf16x8 __attribute__((ext_vector_type(8)));
typedef unsigned short u16;
typedef u16 u16x8 __attribute__((ext_vector_type(8)));

static __device__ __forceinline__ u16 f2b(float f) {
  union { float f; unsigned u; } a; a.f = f;
  unsigned u = a.u;
  u += 0x7fffu + ((u >> 16) & 1u);   // RNE
  return (u16)(u >> 16);
}
static __device__ __forceinline__ float b2f(u16 b) {
  union { float f; unsigned u; } a; a.u = ((unsigned)b) << 16; return a.f;
}
static __device__ __forceinline__ float hsum4(f32x4 v) { return v[0] + v[1] + v[2] + v[3]; }

// ---------------- Kernel 1: RMSNorm + QKV 1x1 conv (fp32), writes bf16 q/k/v ----
// grid 288 (16 pixels/block), block 256
__global__ __launch_bounds__(256) void k_norm_qkv(
    const float* __restrict__ x, const float* __restrict__ gamma,
    const float* __restrict__ wqkv,
    u16* __restrict__ q, u16* __restrict__ kk, u16* __restrict__ vv)
{
  __shared__ __align__(16) float xs[16][260];   // stride 260: 16B-aligned rows, 2-way banks
  __shared__ float g1[CDIM];
  __shared__ float red[4][16];
  __shared__ float rsh[16];
  const int t = threadIdx.x;
  const int blk = blockIdx.x;
  const int b = blk / 144;
  const int p0 = (blk % 144) * 16;
  g1[t] = 1.0f + gamma[t];
  const int pp = t & 15;
  const int cg = t >> 4;
  const float* xb = x + (size_t)b * CDIM * NPIX + p0 + pp;
  float ssq = 0.f;
#pragma unroll
  for (int i = 0; i < 16; ++i) {
    const int c = i * 16 + cg;
    const float v = xb[(size_t)c * NPIX];
    xs[pp][c] = v;
    ssq += v * v;
  }
  ssq += __shfl_xor(ssq, 16);
  ssq += __shfl_xor(ssq, 32);
  if ((t & 63) < 16) red[t >> 6][t & 15] = ssq;
  __syncthreads();
  if (t < 16) {
    const float s = red[0][t] + red[1][t] + red[2][t] + red[3][t];
    rsh[t] = 16.0f / fmaxf(sqrtf(s), 1e-12f);   // sqrt(CDIM)=16
  }
  __syncthreads();
  {
    const float rs = rsh[pp];
#pragma unroll
    for (int i = 0; i < 16; ++i) {
      const int c = i * 16 + cg;
      xs[pp][c] *= rs * g1[c];
    }
  }
  __syncthreads();

  const int ph = t & 7;
  const int og = t >> 3;          // 32 output groups of 48 rows
  const int pA = ph * 2, pB = pA + 1;
  const int gA = p0 + pA;
#pragma unroll 1
  for (int chunk = 0; chunk < 6; ++chunk) {
    const int o0 = og * 48 + chunk * 8;  // 8 consecutive outputs, same qkv region & head
    f32x4 acc0[8], acc1[8];
#pragma unroll
    for (int j = 0; j < 8; ++j) {
      f32x4 z = {0.f, 0.f, 0.f, 0.f};
      acc0[j] = z; acc1[j] = z;
    }
    for (int c4 = 0; c4 < 64; ++c4) {
      const f32x4 xa = *(const f32x4*)&xs[pA][c4 * 4];
      const f32x4 xv = *(const f32x4*)&xs[pB][c4 * 4];
#pragma unroll
      for (int j = 0; j < 8; ++j) {
        const f32x4 wv = *(const f32x4*)&wqkv[(size_t)(o0 + j) * CDIM + c4 * 4];
        acc0[j] += xa * wv;
        acc1[j] += xv * wv;
      }
    }
    const int r = o0 >> 9;                     // 0=q 1=k 2=v
    const float sc = (r == 0) ? QSCALE : 1.0f;
    u16x8 out0, out1;
#pragma unroll
    for (int j = 0; j < 8; ++j) {
      out0[j] = f2b(hsum4(acc0[j]) * sc);
      out1[j] = f2b(hsum4(acc1[j]) * sc);
    }
    const int oo = o0 & 511;
    const int h = oo >> 6;
    const int d0 = oo & 63;
    u16* dst;
    if (r == 0)      dst = q  + (((size_t)(b * NHEAD + h)) * NPIX + gA) * DH + d0;
    else if (r == 1) dst = kk + (((size_t)(b * NHEAD + h)) * NKV + NMEM + gA) * DH + d0;
    else             dst = vv + (((size_t)(b * NHEAD + h)) * NKV + NMEM + gA) * DH + d0;
    *(u16x8*)dst = out0;
    *(u16x8*)(dst + DH) = out1;   // next pixel row
  }
}

// ---------------- Kernel 2: fill memory kv tokens (rows 0..3 of k/v) ------------
__global__ __launch_bounds__(256) void k_fillmem(const float* __restrict__ mem_kv,
                                                 u16* __restrict__ kk, u16* __restrict__ vv)
{
  const int idx = blockIdx.x * 256 + threadIdx.x;  // 0..4095 = b,h,m,d
  const int d = idx & 63;
  const int m = (idx >> 6) & 3;
  const int h = (idx >> 8) & 7;
  const int b = idx >> 11;
  const float mk = mem_kv[((size_t)h * NMEM + m) * DH + d];
  const float mv = mem_kv[(((size_t)NHEAD + h) * NMEM + m) * DH + d];
  const size_t o = (((size_t)(b * NHEAD + h)) * NKV + m) * DH + d;
  kk[o] = f2b(mk);
  vv[o] = f2b(mv);
}

// ---------------- Kernel 3: flash attention, bf16 MFMA --------------------------
// grid (36, 16) = (qtile, b*h); block 256 = 4 waves x 16 q-rows; KT = 64
__global__ __launch_bounds__(256) void k_attn(
    const u16* __restrict__ q, const u16* __restrict__ kk, const u16* __restrict__ vv,
    float* __restrict__ ao)
{
  __shared__ __align__(16) u16 vt[64 * 72];      // V^T, block-XOR swizzled
  __shared__ __align__(16) u16 ps[4][16 * 72];   // per-wave P (bf16)
  const int t = threadIdx.x;
  const int w = t >> 6, l = t & 63;
  const int li = l & 15, kg = l >> 4;
  const int bh = blockIdx.y;
  const int b = bh >> 3, h = bh & 7;
  const int qbase = blockIdx.x * 64 + w * 16;
  const u16* qp = q + ((size_t)bh * NPIX + qbase) * DH;
  const u16* kp = kk + (size_t)bh * NKV * DH;
  const u16* vp = vv + (size_t)bh * NKV * DH;

  // Q A-fragments: lane holds row=li, k(d)=kg*8+e (+32)
  const bf16x8 aq0 = *(const bf16x8*)&qp[li * DH + kg * 8];
  const bf16x8 aq1 = *(const bf16x8*)&qp[li * DH + 32 + kg * 8];

  f32x4 acc[4];
  float m_r[4], l_r[4];
#pragma unroll
  for (int r = 0; r < 4; ++r) { m_r[r] = -1e30f; l_r[r] = 0.f; }
#pragma unroll
  for (int df = 0; df < 4; ++df) { f32x4 z = {0.f,0.f,0.f,0.f}; acc[df] = z; }

  const int NT = (NKV + 63) / 64;  // 37
  for (int tile = 0; tile < NT; ++tile) {
    const int kbase = tile * 64;
    __syncthreads();   // previous tile's vt/ps reads done
    // stage V transposed into LDS (swizzled blocks to dodge bank conflicts)
#pragma unroll
    for (int it = 0; it < 2; ++it) {
      const int jj = (t >> 3) + it * 32;
      const int dd0 = (t & 7) * 8;
      const int j = kbase + jj;
      u16x8 vrow = {0,0,0,0,0,0,0,0};
      if (j < NKV) vrow = *(const u16x8*)&vp[(size_t)j * DH + dd0];
      const int jhi = jj >> 3;
#pragma unroll
      for (int e = 0; e < 8; ++e) {
        const int d = dd0 + e;
        const int sj = (jj & 7) | (((jhi ^ (d >> 3)) & 7) << 3);
        vt[d * 72 + sj] = vrow[e];
      }
    }
    // S = q_scaled . k^T : B-frag straight from global k (k-dim = d is contiguous)
    f32x4 s[4];
#pragma unroll
    for (int jf = 0; jf < 4; ++jf) {
      const int j = kbase + jf * 16 + li;
      const int jc = (j < NKV) ? j : (NKV - 1);
      const bf16x8 bk0 = *(const bf16x8*)&kp[(size_t)jc * DH + kg * 8];
      const bf16x8 bk1 = *(const bf16x8*)&kp[(size_t)jc * DH + 32 + kg * 8];
      f32x4 sf = {0.f,0.f,0.f,0.f};
      sf = __builtin_amdgcn_mfma_f32_16x16x32_bf16(aq0, bk0, sf, 0, 0, 0);
      sf = __builtin_amdgcn_mfma_f32_16x16x32_bf16(aq1, bk1, sf, 0, 0, 0);
      if (j >= NKV) { sf[0] = -1e30f; sf[1] = -1e30f; sf[2] = -1e30f; sf[3] = -1e30f; }
      s[jf] = sf;
    }
    // online softmax; row r of this lane = kg*4 + r, held by 16 consecutive lanes
    float alpha[4];
#pragma unroll
    for (int r = 0; r < 4; ++r) {
      float mx = fmaxf(fmaxf(s[0][r], s[1][r]), fmaxf(s[2][r], s[3][r]));
      mx = fmaxf(mx, __shfl_xor(mx, 1));
      mx = fmaxf(mx, __shfl_xor(mx, 2));
      mx = fmaxf(mx, __shfl_xor(mx, 4));
      mx = fmaxf(mx, __shfl_xor(mx, 8));
      const float mn = fmaxf(m_r[r], mx);
      alpha[r] = __expf(m_r[r] - mn);
      m_r[r] = mn;
      const int row = kg * 4 + r;
      float pq = 0.f;
#pragma unroll
      for (int jf = 0; jf < 4; ++jf) {
        const float pv = __expf(s[jf][r] - mn);
        const u16 pb = f2b(pv);
        ps[w][row * 72 + jf * 16 + li] = pb;
        pq += b2f(pb);
      }
      pq += __shfl_xor(pq, 1);
      pq += __shfl_xor(pq, 2);
      pq += __shfl_xor(pq, 4);
      pq += __shfl_xor(pq, 8);
      l_r[r] = l_r[r] * alpha[r] + pq;
    }
    __syncthreads();   // vt + ps visible
    // rescale accumulators
#pragma unroll
    for (int df = 0; df < 4; ++df)
#pragma unroll
      for (int r = 0; r < 4; ++r) acc[df][r] *= alpha[r];
    // PV: A = P from LDS, B = V^T from swizzled LDS
    const bf16x8 ap0 = *(const bf16x8*)&ps[w][li * 72 + kg * 8];
    const bf16x8 ap1 = *(const bf16x8*)&ps[w][li * 72 + 32 + kg * 8];
#pragma unroll
    for (int df = 0; df < 4; ++df) {
      const int d = df * 16 + li;
      const int blk0 = (kg ^ (d >> 3)) & 7;
      const int blk1 = ((kg + 4) ^ (d >> 3)) & 7;
      const bf16x8 bv0 = *(const bf16x8*)&vt[d * 72 + blk0 * 8];
      const bf16x8 bv1 = *(const bf16x8*)&vt[d * 72 + blk1 * 8];
      acc[df] = __builtin_amdgcn_mfma_f32_16x16x32_bf16(ap0, bv0, acc[df], 0, 0, 0);
      acc[df] = __builtin_amdgcn_mfma_f32_16x16x32_bf16(ap1, bv1, acc[df], 0, 0, 0);
    }
  }
  // epilogue: ao[b][p][h*64+d] = acc / l
#pragma unroll
  for (int df = 0; df < 4; ++df) {
    const int d = h * DH + df * 16 + li;
#pragma unroll
    for (int r = 0; r < 4; ++r) {
      const int p = qbase + kg * 4 + r;
      ao[((size_t)b * NPIX + p) * HID + d] = acc[df][r] / l_r[r];
    }
  }
}

// ---------------- Kernel 4: out 1x1 conv (fp32) ---------------------------------
// grid 288 (16 pixels/block), block 256
__global__ __launch_bounds__(256) void k_out(
    const float* __restrict__ ao, const float* __restrict__ wout, float* __restrict__ out)
{
  __shared__ __align__(16) float as[16][516];
  const int t = threadIdx.x;
  const int blk = blockIdx.x;
  const int b = blk / 144;
  const int p0 = (blk % 144) * 16;
  const float* aop = ao + ((size_t)b * NPIX + p0) * HID;
#pragma unroll
  for (int i = 0; i < 32; ++i) {
    const int idx = t + i * 256;
    as[idx >> 9][idx & 511] = aop[((size_t)(idx >> 9)) * HID + (idx & 511)];
  }
  __syncthreads();
  const int ph = t & 7, og = t >> 3;
  const int pA = ph * 2, pB = pA + 1;
  f32x4 acc0[8], acc1[8];
#pragma unroll
  for (int j = 0; j < 8; ++j) {
    f32x4 z = {0.f, 0.f, 0.f, 0.f};
    acc0[j] = z; acc1[j] = z;
  }
  for (int c4 = 0; c4 < 128; ++c4) {
    const f32x4 xa = *(const f32x4*)&as[pA][c4 * 4];
    const f32x4 xv = *(const f32x4*)&as[pB][c4 * 4];
#pragma unroll
    for (int j = 0; j < 8; ++j) {
      const f32x4 wv = *(const f32x4*)&wout[(size_t)(og * 8 + j) * HID + c4 * 4];
      acc0[j] += xa * wv;
      acc1[j] += xv * wv;
    }
  }
#pragma unroll
  for (int j = 0; j < 8; ++j) {
    const int o = og * 8 + j;
    float* dst = out + ((size_t)b * CDIM + o) * NPIX + p0;
    dst[pA] = hsum4(acc0[j]);
    dst[pB] = hsum4(acc1[j]);
  }
}

extern "C" void kernel_launch(void* const* d_in, const int* in_sizes, int n_in,
                              void* d_out, int out_size, void* d_ws, size_t ws_size,
                              hipStream_t stream)
{
  const float* x      = (const float*)d_in[0];
  const float* gamma  = (const float*)d_in[1];
  const float* mem_kv = (const float*)d_in[2];
  const float* wqkv   = (const float*)d_in[3];
  const float* wout   = (const float*)d_in[4];
  float* out = (float*)d_out;
  char* ws = (char*)d_ws;
  const size_t QB = (size_t)BATCH * NHEAD * NPIX * DH * sizeof(u16);  // 4,718,592
  const size_t KB = (size_t)BATCH * NHEAD * NKV  * DH * sizeof(u16);  // 4,726,784
  u16* q   = (u16*)ws;
  u16* kk  = (u16*)(ws + QB);
  u16* vv  = (u16*)(ws + QB + KB);
  float* ao = (float*)(ws + QB + 2 * KB);   // + 9,437,184 -> total ~23.6 MB

  k_fillmem<<<dim3(16), dim3(256), 0, stream>>>(mem_kv, kk, vv);
  k_norm_qkv<<<dim3(288), dim3(256), 0, stream>>>(x, gamma, wqkv, q, kk, vv);
  k_attn<<<dim3(36, 16), dim3(256), 0, stream>>>(q, kk, vv, ao);
  k_out<<<dim3(288), dim3(256), 0, stream>>>(ao, wout, out);
}

// Round 2
// 204.956 us; speedup vs baseline: 2.4307x; 2.4307x over previous
//
#include <hip/hip_runtime.h>

#define BATCH 2
#define CDIM 256
#define NPIX 2304      // 48*48
#define NHEAD 8
#define DH 64
#define HID 512
#define NMEM 4
#define NKV 2308       // NMEM + NPIX
#define QSCALE 0.125f  // 64^-0.5
#define WQKV_E 393216  // 1536*256
#define WOUT_E 131072  // 256*512

typedef float f32x4 __attribute__((ext_vector_type(4)));
typedef __bf16 bf16x8 __attribute__((ext_vector_type(8)));
typedef unsigned short u16;
typedef u16 u16x8 __attribute__((ext_vector_type(8)));

static __device__ __forceinline__ u16 f2b(float f) {
  union { float f; unsigned u; } a; a.f = f;
  unsigned u = a.u;
  u += 0x7fffu + ((u >> 16) & 1u);   // RNE
  return (u16)(u >> 16);
}
static __device__ __forceinline__ float b2f(u16 b) {
  union { float f; unsigned u; } a; a.u = ((unsigned)b) << 16; return a.f;
}

// ---------------- Kernel 1: RMSNorm -> xn^T bf16 [b*p][c] -----------------------
// grid 72 (64 pixels/block), block 256
__global__ __launch_bounds__(256) void k_norm(
    const float* __restrict__ x, const float* __restrict__ gamma, u16* __restrict__ xnT)
{
  __shared__ float xs[64][257];
  __shared__ float red[4][64];
  __shared__ float rsh[64];
  __shared__ float g1[CDIM];
  const int t = threadIdx.x;
  const int bp0 = blockIdx.x * 64;
  const int bb = bp0 >= NPIX;
  const int p0 = bp0 - bb * NPIX;
  g1[t] = 1.0f + gamma[t];
  const float* xb = x + (size_t)bb * CDIM * NPIX;
  const int pq = (t & 15) * 4;
  const int cq0 = t >> 4;
#pragma unroll
  for (int it = 0; it < 16; ++it) {
    const int c = it * 16 + cq0;
    const f32x4 v = *(const f32x4*)&xb[(size_t)c * NPIX + p0 + pq];
    xs[pq + 0][c] = v[0]; xs[pq + 1][c] = v[1];
    xs[pq + 2][c] = v[2]; xs[pq + 3][c] = v[3];
  }
  __syncthreads();
  {
    const int p = t & 63, cg = t >> 6;
    float ssq = 0.f;
#pragma unroll
    for (int i = 0; i < 64; ++i) { const float v = xs[p][cg * 64 + i]; ssq += v * v; }
    red[cg][p] = ssq;
  }
  __syncthreads();
  if (t < 64) {
    const float s = red[0][t] + red[1][t] + red[2][t] + red[3][t];
    rsh[t] = 16.0f / fmaxf(sqrtf(s), 1e-12f);   // sqrt(CDIM)=16
  }
  __syncthreads();
#pragma unroll
  for (int it = 0; it < 8; ++it) {
    const int idx = it * 256 + t;
    const int pp = idx >> 5, c0 = (idx & 31) * 8;
    const float rs = rsh[pp];
    u16x8 o;
#pragma unroll
    for (int e = 0; e < 8; ++e) o[e] = f2b(xs[pp][c0 + e] * rs * g1[c0 + e]);
    *(u16x8*)&xnT[(size_t)(bp0 + pp) * CDIM + c0] = o;
  }
}

// ---------------- Kernel 2: cast weights to bf16 (QSCALE folded into q rows) ----
// grid 256, block 256; wb = [wqkv bf16 (1536x256) | wout bf16 (256x512)]
__global__ __launch_bounds__(256) void k_prep_w(
    const float* __restrict__ wqkv, const float* __restrict__ wout, u16* __restrict__ wb)
{
  const int i0 = (blockIdx.x * 256 + threadIdx.x) * 8;
  const float* src;
  float sc = 1.0f;
  if (i0 < WQKV_E) { src = wqkv + i0; if ((i0 >> 8) < 512) sc = QSCALE; }
  else             { src = wout + (i0 - WQKV_E); }
  const f32x4 a = *(const f32x4*)src;
  const f32x4 b = *(const f32x4*)(src + 4);
  u16x8 o;
#pragma unroll
  for (int e = 0; e < 4; ++e) { o[e] = f2b(a[e] * sc); o[e + 4] = f2b(b[e] * sc); }
  *(u16x8*)&wb[i0] = o;
}

// ---------------- Kernel 3: fill memory kv tokens (rows 0..3 of k/v) ------------
__global__ __launch_bounds__(256) void k_fillmem(const float* __restrict__ mem_kv,
                                                 u16* __restrict__ kk, u16* __restrict__ vv)
{
  const int idx = blockIdx.x * 256 + threadIdx.x;  // 0..4095 = b,h,m,d
  const int d = idx & 63;
  const int m = (idx >> 6) & 3;
  const int h = (idx >> 8) & 7;
  const int b = idx >> 11;
  const float mk = mem_kv[((size_t)h * NMEM + m) * DH + d];
  const float mv = mem_kv[(((size_t)NHEAD + h) * NMEM + m) * DH + d];
  const size_t o = (((size_t)(b * NHEAD + h)) * NKV + m) * DH + d;
  kk[o] = f2b(mk);
  vv[o] = f2b(mv);
}

// ---------------- Kernel 4: QKV projection GEMM (bf16 MFMA) ---------------------
// C[p][o] = sum_c xnT[p][c] * wb[o][c];  grid (72, 24), block 256 (4 waves x 16 rows)
__global__ __launch_bounds__(256) void k_qkv(
    const u16* __restrict__ xnT, const u16* __restrict__ wb,
    u16* __restrict__ q, u16* __restrict__ kk, u16* __restrict__ vv)
{
  const int t = threadIdx.x, w = t >> 6, l = t & 63, li = l & 15, kg = l >> 4;
  const int m0 = blockIdx.x * 64 + w * 16;
  const int n0 = blockIdx.y * 64;
  const u16* ap = xnT + (size_t)(m0 + li) * CDIM + kg * 8;
  f32x4 acc[4];
#pragma unroll
  for (int cf = 0; cf < 4; ++cf) { f32x4 z = {0.f,0.f,0.f,0.f}; acc[cf] = z; }
#pragma unroll
  for (int ks = 0; ks < 8; ++ks) {
    const bf16x8 af = *(const bf16x8*)(ap + ks * 32);
#pragma unroll
    for (int cf = 0; cf < 4; ++cf) {
      const int o = n0 + cf * 16 + li;
      const bf16x8 bfr = *(const bf16x8*)(wb + (size_t)o * CDIM + ks * 32 + kg * 8);
      acc[cf] = __builtin_amdgcn_mfma_f32_16x16x32_bf16(af, bfr, acc[cf], 0, 0, 0);
    }
  }
  const int bb = (m0 >= NPIX) ? 1 : 0;
  const int plbase = m0 - bb * NPIX + kg * 4;
#pragma unroll
  for (int cf = 0; cf < 4; ++cf) {
    const int o0f = n0 + cf * 16;          // uniform over lanes
    const int r = o0f >> 9, oo = o0f & 511, h = oo >> 6, d = (oo & 63) + li;
    u16* base;
    if (r == 0)      base = q  + ((size_t)(bb * NHEAD + h) * NPIX + plbase) * DH + d;
    else if (r == 1) base = kk + ((size_t)(bb * NHEAD + h) * NKV + NMEM + plbase) * DH + d;
    else             base = vv + ((size_t)(bb * NHEAD + h) * NKV + NMEM + plbase) * DH + d;
#pragma unroll
    for (int rr = 0; rr < 4; ++rr) base[(size_t)rr * DH] = f2b(acc[cf][rr]);
  }
}

// ---------------- Kernel 5: flash attention, bf16 MFMA --------------------------
// grid (36, 16) = (qtile, b*h); block 256 = 4 waves x 16 q-rows; KT = 64
__global__ __launch_bounds__(256) void k_attn(
    const u16* __restrict__ q, const u16* __restrict__ kk, const u16* __restrict__ vv,
    u16* __restrict__ aoB)
{
  __shared__ __align__(16) u16 vt[64 * 72];      // V^T, block-XOR swizzled
  __shared__ __align__(16) u16 ps[4][16 * 72];   // per-wave P (bf16)
  const int t = threadIdx.x;
  const int w = t >> 6, l = t & 63;
  const int li = l & 15, kg = l >> 4;
  const int bh = blockIdx.y;
  const int b = bh >> 3, h = bh & 7;
  const int qbase = blockIdx.x * 64 + w * 16;
  const u16* qp = q + ((size_t)bh * NPIX + qbase) * DH;
  const u16* kp = kk + (size_t)bh * NKV * DH;
  const u16* vp = vv + (size_t)bh * NKV * DH;

  const bf16x8 aq0 = *(const bf16x8*)&qp[li * DH + kg * 8];
  const bf16x8 aq1 = *(const bf16x8*)&qp[li * DH + 32 + kg * 8];

  f32x4 acc[4];
  float m_r[4], l_r[4];
#pragma unroll
  for (int r = 0; r < 4; ++r) { m_r[r] = -1e30f; l_r[r] = 0.f; }
#pragma unroll
  for (int df = 0; df < 4; ++df) { f32x4 z = {0.f,0.f,0.f,0.f}; acc[df] = z; }

  const int NT = (NKV + 63) / 64;  // 37
  for (int tile = 0; tile < NT; ++tile) {
    const int kbase = tile * 64;
    __syncthreads();   // previous tile's vt/ps reads done
#pragma unroll
    for (int it = 0; it < 2; ++it) {
      const int jj = (t >> 3) + it * 32;
      const int dd0 = (t & 7) * 8;
      const int j = kbase + jj;
      u16x8 vrow = {0,0,0,0,0,0,0,0};
      if (j < NKV) vrow = *(const u16x8*)&vp[(size_t)j * DH + dd0];
      const int jhi = jj >> 3;
#pragma unroll
      for (int e = 0; e < 8; ++e) {
        const int d = dd0 + e;
        const int sj = (jj & 7) | (((jhi ^ (d >> 3)) & 7) << 3);
        vt[d * 72 + sj] = vrow[e];
      }
    }
    f32x4 s[4];
#pragma unroll
    for (int jf = 0; jf < 4; ++jf) {
      const int j = kbase + jf * 16 + li;
      const int jc = (j < NKV) ? j : (NKV - 1);
      const bf16x8 bk0 = *(const bf16x8*)&kp[(size_t)jc * DH + kg * 8];
      const bf16x8 bk1 = *(const bf16x8*)&kp[(size_t)jc * DH + 32 + kg * 8];
      f32x4 sf = {0.f,0.f,0.f,0.f};
      sf = __builtin_amdgcn_mfma_f32_16x16x32_bf16(aq0, bk0, sf, 0, 0, 0);
      sf = __builtin_amdgcn_mfma_f32_16x16x32_bf16(aq1, bk1, sf, 0, 0, 0);
      if (j >= NKV) { sf[0] = -1e30f; sf[1] = -1e30f; sf[2] = -1e30f; sf[3] = -1e30f; }
      s[jf] = sf;
    }
    float alpha[4];
#pragma unroll
    for (int r = 0; r < 4; ++r) {
      float mx = fmaxf(fmaxf(s[0][r], s[1][r]), fmaxf(s[2][r], s[3][r]));
      mx = fmaxf(mx, __shfl_xor(mx, 1));
      mx = fmaxf(mx, __shfl_xor(mx, 2));
      mx = fmaxf(mx, __shfl_xor(mx, 4));
      mx = fmaxf(mx, __shfl_xor(mx, 8));
      const float mn = fmaxf(m_r[r], mx);
      alpha[r] = __expf(m_r[r] - mn);
      m_r[r] = mn;
      const int row = kg * 4 + r;
      float pq = 0.f;
#pragma unroll
      for (int jf = 0; jf < 4; ++jf) {
        const float pv = __expf(s[jf][r] - mn);
        const u16 pb = f2b(pv);
        ps[w][row * 72 + jf * 16 + li] = pb;
        pq += b2f(pb);
      }
      pq += __shfl_xor(pq, 1);
      pq += __shfl_xor(pq, 2);
      pq += __shfl_xor(pq, 4);
      pq += __shfl_xor(pq, 8);
      l_r[r] = l_r[r] * alpha[r] + pq;
    }
    __syncthreads();   // vt + ps visible
#pragma unroll
    for (int df = 0; df < 4; ++df)
#pragma unroll
      for (int r = 0; r < 4; ++r) acc[df][r] *= alpha[r];
    const bf16x8 ap0 = *(const bf16x8*)&ps[w][li * 72 + kg * 8];
    const bf16x8 ap1 = *(const bf16x8*)&ps[w][li * 72 + 32 + kg * 8];
#pragma unroll
    for (int df = 0; df < 4; ++df) {
      const int d = df * 16 + li;
      const int blk0 = (kg ^ (d >> 3)) & 7;
      const int blk1 = ((kg + 4) ^ (d >> 3)) & 7;
      const bf16x8 bv0 = *(const bf16x8*)&vt[d * 72 + blk0 * 8];
      const bf16x8 bv1 = *(const bf16x8*)&vt[d * 72 + blk1 * 8];
      acc[df] = __builtin_amdgcn_mfma_f32_16x16x32_bf16(ap0, bv0, acc[df], 0, 0, 0);
      acc[df] = __builtin_amdgcn_mfma_f32_16x16x32_bf16(ap1, bv1, acc[df], 0, 0, 0);
    }
  }
  // epilogue: aoB[b*p][h*64+d] = bf16(acc / l)
#pragma unroll
  for (int df = 0; df < 4; ++df) {
    const int d = h * DH + df * 16 + li;
#pragma unroll
    for (int r = 0; r < 4; ++r) {
      const int p = qbase + kg * 4 + r;
      aoB[((size_t)b * NPIX + p) * HID + d] = f2b(acc[df][r] / l_r[r]);
    }
  }
}

// ---------------- Kernel 6: out projection GEMM (bf16 MFMA) ---------------------
// out[b][o][p] = sum_c aoB[p][c] * wob[o][c];  grid (144, 8), block 256
__global__ __launch_bounds__(256) void k_outg(
    const u16* __restrict__ aoB, const u16* __restrict__ wob, float* __restrict__ out)
{
  const int t = threadIdx.x, w = t >> 6, l = t & 63, li = l & 15, kg = l >> 4;
  const int wm = w >> 1, wn = w & 1;
  const int m0 = blockIdx.x * 32 + wm * 16;
  const int n0 = blockIdx.y * 32 + wn * 16;
  const u16* ap = aoB + (size_t)(m0 + li) * HID + kg * 8;
  const u16* bp = wob + (size_t)(n0 + li) * HID + kg * 8;
  f32x4 acc = {0.f, 0.f, 0.f, 0.f};
#pragma unroll
  for (int ks = 0; ks < 16; ++ks) {
    const bf16x8 af = *(const bf16x8*)(ap + ks * 32);
    const bf16x8 bf = *(const bf16x8*)(bp + ks * 32);
    acc = __builtin_amdgcn_mfma_f32_16x16x32_bf16(af, bf, acc, 0, 0, 0);
  }
  const int bb = (m0 >= NPIX) ? 1 : 0;
  const int pl = m0 - bb * NPIX + kg * 4;
  const int o = n0 + li;
  *(f32x4*)&out[((size_t)(bb * CDIM + o)) * NPIX + pl] = acc;
}

extern "C" void kernel_launch(void* const* d_in, const int* in_sizes, int n_in,
                              void* d_out, int out_size, void* d_ws, size_t ws_size,
                              hipStream_t stream)
{
  const float* x      = (const float*)d_in[0];
  const float* gamma  = (const float*)d_in[1];
  const float* mem_kv = (const float*)d_in[2];
  const float* wqkv   = (const float*)d_in[3];
  const float* wout   = (const float*)d_in[4];
  float* out = (float*)d_out;
  char* ws = (char*)d_ws;
  const size_t XNT = (size_t)BATCH * NPIX * CDIM * sizeof(u16);       // 2,359,296
  const size_t WB  = (size_t)(WQKV_E + WOUT_E) * sizeof(u16);         // 1,048,576
  const size_t QB  = (size_t)BATCH * NHEAD * NPIX * DH * sizeof(u16); // 4,718,592
  const size_t KB  = (size_t)BATCH * NHEAD * NKV  * DH * sizeof(u16); // 4,726,784
  u16* xnT = (u16*)ws;
  u16* wb  = (u16*)(ws + XNT);
  u16* q   = (u16*)(ws + XNT + WB);
  u16* kk  = (u16*)(ws + XNT + WB + QB);
  u16* vv  = (u16*)(ws + XNT + WB + QB + KB);
  u16* aoB = (u16*)(ws + XNT + WB + QB + 2 * KB);  // + 4,718,592 -> ~21.3 MB total

  k_prep_w<<<dim3(256), dim3(256), 0, stream>>>(wqkv, wout, wb);
  k_fillmem<<<dim3(16), dim3(256), 0, stream>>>(mem_kv, kk, vv);
  k_norm<<<dim3(72), dim3(256), 0, stream>>>(x, gamma, xnT);
  k_qkv<<<dim3(72, 24), dim3(256), 0, stream>>>(xnT, wb, q, kk, vv);
  k_attn<<<dim3(36, 16), dim3(256), 0, stream>>>(q, kk, vv, aoB);
  k_outg<<<dim3(144, 8), dim3(256), 0, stream>>>(aoB, wb + WQKV_E, out);
}